// Round 6
// baseline (168.823 us; speedup 1.0000x reference)
//
#include <hip/hip_runtime.h>
#include <math.h>

#define NCAT  5
#define BATCH 64
#define ELEMS 196608          // C*H*W = 3*256*256
#define EPSV  1e-6f

// native 4-float vector (HIP float4 is a class; this one works with
// __builtin_nontemporal_load and supports componentwise arithmetic)
typedef float v4f __attribute__((ext_vector_type(4)));

// ---- pass 1 geometry (strided batch-reduction over `un`, 4 KB bursts) ----
#define WIN   1024             // floats per block window (4 KB per batch burst)
#define WIN4  (WIN / 4)        // 256 float4 per window
#define NCHK  4                // 1-KB wave requests per window
#define NBLK1 (ELEMS / WIN)    // 192 blocks
#define CHUNK 16               // batches per wave (4 waves cover 64)
#define GRP   4                // batches per pipeline stage (16 loads in flight)

// ---- pass 2 geometry (streaming over clean/restored/s) ----
#define NSLAB  12              // slabs per batch (fat blocks: 64 KB/array/block)
#define SLABSZ (ELEMS / NSLAB) // 16384 positions per slab
#define NBLK2  (BATCH * NSLAB) // 768 blocks

// d_ws layout (floats):
//   s_buf  [NCAT][ELEMS]   (per-cat scale map 1/un_map)
//   p1     [NCAT][NBLK1]   (per-cat un sums)
//   p2     [2][NBLK2]      (row0 = scaled sums, row1 = abs sums)
#define WS_S   0
#define WS_P1  (NCAT * ELEMS)
#define WS_P2  (WS_P1 + NCAT * NBLK1)

static __device__ __forceinline__ v4f vfma(float m, v4f a, v4f b) {
    v4f r;
    r.x = fmaf(m, a.x, b.x);
    r.y = fmaf(m, a.y, b.y);
    r.z = fmaf(m, a.z, b.z);
    r.w = fmaf(m, a.w, b.w);
    return r;
}

// ---------------------------------------------------------------------------
// Pass 1: un_sum[cat][pos] over batches (4 KB sequential bursts per stream),
// invert to s, emit per-cat un sums.
// ---------------------------------------------------------------------------
__global__ __launch_bounds__(256, 1) void pass1_kernel(
    const float* __restrict__ un,
    const int*   __restrict__ de_id,
    float*       __restrict__ s_buf,
    float*       __restrict__ p1)
{
    __shared__ int   sh_de[BATCH];
    __shared__ float sh_inv[NCAT];
    __shared__ v4f   sbuf[2][NCAT][WIN4];   // 40 KB merge buffer

    const int tid  = threadIdx.x;
    const int lane = tid & 63;
    const int wave = tid >> 6;

    if (tid < BATCH) {
        int k = de_id[tid];
        sh_de[tid] = k;
        #pragma unroll
        for (int j = 0; j < NCAT; ++j) {
            unsigned long long m = __ballot(k == j);
            if (tid == j) {
                int c = __popcll(m);
                sh_inv[j] = 1.0f / (float)(c > 0 ? c : 1);
            }
        }
    }
    __syncthreads();

    const size_t STR4 = ELEMS / 4;
    const v4f* up4 = (const v4f*)(un) + (size_t)blockIdx.x * WIN4 + lane;

    v4f acc[NCAT][NCHK];
    #pragma unroll
    for (int j = 0; j < NCAT; ++j)
        #pragma unroll
        for (int c = 0; c < NCHK; ++c) acc[j][c] = (v4f)0.f;

    // double-buffered register pipeline: GRP batches x NCHK chunks per stage
    v4f ub[2][GRP][NCHK];
    #pragma unroll
    for (int i = 0; i < GRP; ++i)
        #pragma unroll
        for (int c = 0; c < NCHK; ++c)
            ub[0][i][c] = up4[(size_t)(wave * CHUNK + i) * STR4 + c * 64];

    #pragma unroll
    for (int g = 0; g < CHUNK / GRP; ++g) {
        const int cur = g & 1;
        const int nxt = cur ^ 1;
        if (g < CHUNK / GRP - 1) {
            #pragma unroll
            for (int i = 0; i < GRP; ++i)
                #pragma unroll
                for (int c = 0; c < NCHK; ++c)
                    ub[nxt][i][c] =
                        up4[(size_t)(wave * CHUNK + (g + 1) * GRP + i) * STR4 + c * 64];
        }
        #pragma unroll
        for (int i = 0; i < GRP; ++i) {
            const int k = sh_de[wave * CHUNK + g * GRP + i];
            #pragma unroll
            for (int j = 0; j < NCAT; ++j) {
                float m = (k == j) ? 1.0f : 0.0f;
                #pragma unroll
                for (int c = 0; c < NCHK; ++c)
                    acc[j][c] = vfma(m, ub[cur][i][c], acc[j][c]);
            }
        }
    }

    // ---- merge the 4 batch-chunk waves into wave 0 (2-round LDS tree) ----
    if (wave >= 2) {
        #pragma unroll
        for (int j = 0; j < NCAT; ++j)
            #pragma unroll
            for (int c = 0; c < NCHK; ++c)
                sbuf[wave - 2][j][c * 64 + lane] = acc[j][c];
    }
    __syncthreads();
    if (wave < 2) {
        #pragma unroll
        for (int j = 0; j < NCAT; ++j)
            #pragma unroll
            for (int c = 0; c < NCHK; ++c)
                acc[j][c] += sbuf[wave][j][c * 64 + lane];
    }
    __syncthreads();
    if (wave == 1) {
        #pragma unroll
        for (int j = 0; j < NCAT; ++j)
            #pragma unroll
            for (int c = 0; c < NCHK; ++c)
                sbuf[0][j][c * 64 + lane] = acc[j][c];
    }
    __syncthreads();
    if (wave == 0) {
        float vals[NCAT];
        #pragma unroll
        for (int j = 0; j < NCAT; ++j) {
            float tot = 0.f;
            #pragma unroll
            for (int c = 0; c < NCHK; ++c) {
                v4f a = acc[j][c] + sbuf[0][j][c * 64 + lane];

                v4f um;
                um.x = fmaf(a.x, sh_inv[j], EPSV);
                um.y = fmaf(a.y, sh_inv[j], EPSV);
                um.z = fmaf(a.z, sh_inv[j], EPSV);
                um.w = fmaf(a.w, sh_inv[j], EPSV);
                v4f sv;
                sv.x = 1.0f / um.x;
                sv.y = 1.0f / um.y;
                sv.z = 1.0f / um.z;
                sv.w = 1.0f / um.w;
                ((v4f*)s_buf)[(size_t)j * STR4 + (size_t)blockIdx.x * WIN4
                              + c * 64 + lane] = sv;

                tot += (a.x + a.y) + (a.z + a.w);
            }
            vals[j] = tot;
        }

        #pragma unroll
        for (int i = 0; i < NCAT; ++i) {
            float v = vals[i];
            #pragma unroll
            for (int off = 32; off >= 1; off >>= 1)
                v += __shfl_down(v, off, 64);
            vals[i] = v;
        }
        if (lane == 0) {
            #pragma unroll
            for (int i = 0; i < NCAT; ++i)
                p1[i * NBLK1 + blockIdx.x] = vals[i];
        }
    }
}

// ---------------------------------------------------------------------------
// Pass 2: streaming |clean-restored| and |.|*s over fat contiguous slabs.
// ---------------------------------------------------------------------------
__global__ __launch_bounds__(256) void pass2_kernel(
    const float* __restrict__ restored,
    const float* __restrict__ clean,
    const int*   __restrict__ de_id,
    const float* __restrict__ s_buf,
    float*       __restrict__ p2)
{
    __shared__ float sred[4][2];

    const int tid  = threadIdx.x;
    const int lane = tid & 63;
    const int wave = tid >> 6;

    const int b   = blockIdx.x / NSLAB;
    const int sl  = blockIdx.x % NSLAB;
    const int cat = de_id[b];                 // block-uniform scalar

    // float4-unit base: slab sl, wave-quarter, lane
    const size_t base4 = (size_t)sl * (SLABSZ / 4) + (size_t)wave * (SLABSZ / 16)
                       + (size_t)lane;
    const v4f* cp = (const v4f*)(clean)    + (size_t)b   * (ELEMS / 4) + base4;
    const v4f* rp = (const v4f*)(restored) + (size_t)b   * (ELEMS / 4) + base4;
    const v4f* sp = (const v4f*)(s_buf)    + (size_t)cat * (ELEMS / 4) + base4;

    float ssum = 0.f, asum = 0.f;
    // (SLABSZ/16) float4 per wave / 64 lanes = 16 iterations
    #pragma unroll 16
    for (int it = 0; it < SLABSZ / 16 / 64; ++it) {
        v4f c  = __builtin_nontemporal_load(cp + it * 64);   // read-once
        v4f r  = __builtin_nontemporal_load(rp + it * 64);   // read-once
        v4f sv = sp[it * 64];                                // L2/L3-hot
        float a0 = fabsf(c.x - r.x);
        float a1 = fabsf(c.y - r.y);
        float a2 = fabsf(c.z - r.z);
        float a3 = fabsf(c.w - r.w);
        asum += (a0 + a1) + (a2 + a3);
        ssum = fmaf(a0, sv.x, ssum);
        ssum = fmaf(a1, sv.y, ssum);
        ssum = fmaf(a2, sv.z, ssum);
        ssum = fmaf(a3, sv.w, ssum);
    }

    #pragma unroll
    for (int off = 32; off >= 1; off >>= 1) {
        ssum += __shfl_down(ssum, off, 64);
        asum += __shfl_down(asum, off, 64);
    }
    if (lane == 0) { sred[wave][0] = ssum; sred[wave][1] = asum; }
    __syncthreads();
    if (tid == 0) {
        float s = sred[0][0] + sred[1][0] + sred[2][0] + sred[3][0];
        float a = sred[0][1] + sred[1][1] + sred[2][1] + sred[3][1];
        p2[blockIdx.x]         = s;
        p2[NBLK2 + blockIdx.x] = a;
    }
}

// ---------------------------------------------------------------------------
// Epilogue: gather p2 by category, reduce p1, final 21-output math.
// ---------------------------------------------------------------------------
__global__ __launch_bounds__(1024) void epilogue_kernel(
    const int*   __restrict__ de_id,
    const float* __restrict__ p1,
    const float* __restrict__ p2,
    float*       __restrict__ out)
{
    __shared__ int   sh_cnt[NCAT];
    __shared__ int   sh_cat[BATCH];
    __shared__ float sh_acc[3 * NCAT];

    const int tid  = threadIdx.x;
    const int lane = tid & 63;
    const int wave = tid >> 6;

    if (tid < BATCH) {
        int k = de_id[tid];
        sh_cat[tid] = k;
        #pragma unroll
        for (int j = 0; j < NCAT; ++j) {
            unsigned long long m = __ballot(k == j);
            if (tid == j) sh_cnt[j] = __popcll(m);
        }
    }
    __syncthreads();

    float v = 0.f;
    if (wave < 5) {                       // scaled sums per cat
        for (int it = 0; it < NBLK2 / 64; ++it) {
            int col = it * 64 + lane;
            v += (sh_cat[col / NSLAB] == wave) ? p2[col] : 0.f;
        }
    } else if (wave < 10) {               // abs sums per cat
        const int j = wave - 5;
        for (int it = 0; it < NBLK2 / 64; ++it) {
            int col = it * 64 + lane;
            v += (sh_cat[col / NSLAB] == j) ? p2[NBLK2 + col] : 0.f;
        }
    } else if (wave < 15) {               // un sums per cat
        const int j = wave - 10;
        for (int it = 0; it < NBLK1 / 64; ++it)
            v += p1[j * NBLK1 + it * 64 + lane];
    }
    #pragma unroll
    for (int off = 32; off >= 1; off >>= 1)
        v += __shfl_down(v, off, 64);
    if (lane == 0 && wave < 15) sh_acc[wave] = v;
    __syncthreads();

    if (tid == 0) {
        const float Ef = (float)ELEMS;
        float cum_s = 0.f;
        long  cum_c = 0;
        float total = 0.f;
        int   num   = 0;

        float cat_losses[NCAT], old_loss[NCAT], bn[NCAT], unc_l1[NCAT];

        for (int j = 0; j < NCAT; ++j) {
            cum_s += sh_acc[j];
            cum_c += sh_cnt[j];
            float cum_elems = (float)cum_c * Ef;
            float cum_l1    = cum_s / fmaxf(cum_elems, 1.0f);

            bool  ne   = sh_cnt[j] > 0;
            float safe = (float)(ne ? sh_cnt[j] : 1);

            old_loss[j]  = ne ? sh_acc[NCAT + j] / (safe * Ef) : 0.f;
            float un_num = sh_acc[2 * NCAT + j] / (safe * Ef) + EPSV;
            bn[j]        = ne ? 2.0f * logf(un_num) : 0.f;
            unc_l1[j]    = ne ? cum_l1 : 0.f;
            cat_losses[j] = unc_l1[j] + bn[j];
            total += cat_losses[j];
            num   += ne ? 1 : 0;
        }
        total /= (float)num;

        out[0] = total;
        for (int j = 0; j < NCAT; ++j) {
            out[1 + j]  = cat_losses[j];
            out[6 + j]  = old_loss[j];
            out[11 + j] = bn[j];
            out[16 + j] = unc_l1[j];
        }
    }
}

extern "C" void kernel_launch(void* const* d_in, const int* in_sizes, int n_in,
                              void* d_out, int out_size, void* d_ws, size_t ws_size,
                              hipStream_t stream) {
    (void)in_sizes; (void)n_in; (void)out_size; (void)ws_size;
    const float* restored = (const float*)d_in[0];
    const float* clean    = (const float*)d_in[1];
    const int*   de_id    = (const int*)d_in[2];
    const float* un       = (const float*)d_in[3];
    float* out   = (float*)d_out;
    float* ws    = (float*)d_ws;
    float* s_buf = ws + WS_S;
    float* p1    = ws + WS_P1;
    float* p2    = ws + WS_P2;

    pass1_kernel<<<NBLK1, 256, 0, stream>>>(un, de_id, s_buf, p1);
    pass2_kernel<<<NBLK2, 256, 0, stream>>>(restored, clean, de_id, s_buf, p2);
    epilogue_kernel<<<1, 1024, 0, stream>>>(de_id, p1, p2, out);
}